// Round 2
// baseline (315.262 us; speedup 1.0000x reference)
//
#include <hip/hip_runtime.h>
#include <hip/hip_bf16.h>

#define BATCH 32
#define WDIM 512
#define HDIM 512
#define CDIM 3
#define KPSF 32
#define NPRED (BATCH*WDIM*HDIM*CDIM)  // 25165824

#define TW 88        // tile width  (x): exactly 64 + 15 + 9 taps, multiple of 8
#define TH 63        // tile height (y): 32 + 31
#define TE (TW*TH)   // 5544 per channel
#define TALL (TW*TH*CDIM)  // 16632 dense elements

// LDS map (bytes) — two tiles pipelined in one block:
//   sImgA: [0, 33264)       stage/main tile 1
//   sOutA: [0, 24576)       epilogue-1 staging (aliases sImgA, after main-1)
//   sImgB: [24576, 57840)   stage/main tile 2 (disjoint from sOutA)
//   sOutB: [24576, 49152)   epilogue-2 staging (aliases sImgB, after main-2)
#define SIMG_B_OFF 24576
#define LDS_BYTES 57856      // <= 64KB static; 2 blocks/CU fits 160KB pool

typedef __bf16 bf16x8 __attribute__((ext_vector_type(8)));
typedef float floatx16 __attribute__((ext_vector_type(16)));
typedef float fx4 __attribute__((ext_vector_type(4)));

// Workgroup barrier that does NOT drain vmcnt: only LDS ordering is required;
// global loads/stores stay in flight across it.
__device__ __forceinline__ void barrier_lgkm() {
    __asm__ volatile("s_waitcnt lgkmcnt(0)\n\ts_barrier" ::: "memory");
}

// Pack psf[b,i,j,0,c] (fp32) into MFMA A-fragment order (bf16):
// dst[((c*32 + j)*2 + h)*64 + lane][t] = psf[b=lane&31][i=16h+8*(lane>>5)+t][j][c]
__global__ __launch_bounds__(64) void pack_psf(const float* __restrict__ psf,
                                               __bf16* __restrict__ dst,
                                               float* __restrict__ loss) {
    if (blockIdx.x == 0 && threadIdx.x == 0) *loss = 0.f;
    int idx = blockIdx.x;              // [0,192) = ((c*32 + j)*2 + h)
    int h = idx & 1;
    int j = (idx >> 1) & 31;
    int c = idx >> 6;
    int lane = threadIdx.x;
    int b = lane & 31;
    int q = lane >> 5;
    bf16x8 v;
#pragma unroll
    for (int t = 0; t < 8; ++t) {
        int i = 16*h + 8*q + t;
        v[t] = (__bf16)psf[((size_t)(b*KPSF + i)*KPSF + j)*CDIM + c];
    }
    *(bf16x8*)(dst + (size_t)(idx*64 + lane)*8) = v;
}

__device__ __forceinline__ void stage_tile(__bf16* sImg /* [CDIM][TE] */,
                                           const float* __restrict__ img,
                                           int tid, int x0, int ytile) {
    const bool interior = (x0 >= 15) && (x0 <= WDIM - 73) &&
                          (ytile >= 15) && (ytile <= HDIM - 48);
    if (interior) {
        // float4 path: per x-row, the 189-float column run starts at a uniform
        // misalignment p2; load alignment-shifted float4 slots, scatter to LDS.
        const int col0 = (ytile - 15)*3;           // >= 0
        const int p2 = col0 & 3;
        const float* gb = img + (size_t)(x0 - 15)*(HDIM*CDIM) + (col0 - p2);
#pragma unroll 2
        for (int f = tid; f < 88*48; f += 384) {
            int r = f / 48;                        // x-row 0..87
            int v = f - r*48;                      // float4 slot 0..47
            fx4 val = *(const fx4*)(gb + (size_t)r*(HDIM*CDIM) + 4*v);
            int d = 4*v - p2;                      // col offset of val[0]
#pragma unroll
            for (int u = 0; u < 4; ++u) {
                int dd = d + u;
                if (dd >= 0 && dd < 189) {
                    int yl = (dd*171) >> 9;        // dd/3 for dd<511
                    int cc = dd - 3*yl;
                    sImg[cc*TE + yl*TW + r] = (__bf16)val[u];
                }
            }
        }
    } else {
#pragma unroll 4
        for (int e = tid; e < TALL; e += 384) {
            int xl = e / (TH*CDIM);
            int rr = e - xl*(TH*CDIM);
            int yl = rr / 3;
            int cc = rr - yl*3;
            int xg = x0 + xl - 15;
            int yg = ytile + yl - 15;
            float v = 0.f;
            if ((unsigned)xg < WDIM && (unsigned)yg < HDIM)
                v = img[((size_t)xg*HDIM + yg)*CDIM + cc];
            sImg[cc*TE + yl*TW + xl] = (__bf16)v;
        }
    }
}

__device__ __forceinline__ void main_loop(floatx16 acc[4],
                                          const __bf16* __restrict__ pA,
                                          const __bf16* sIc, int n) {
    bf16x8 A0 = *(const bf16x8*)(pA);
    bf16x8 A1 = *(const bf16x8*)(pA + 512);
#pragma unroll 2
    for (int j = 0; j < 32; ++j) {
        bf16x8 cA0 = A0, cA1 = A1;
        if (j < 31) {
            A0 = *(const bf16x8*)(pA + (size_t)(j+1)*1024);
            A1 = *(const bf16x8*)(pA + (size_t)(j+1)*1024 + 512);
        }
        const __bf16* rowp = sIc + (n + j)*TW;
        bf16x8 C[6];
#pragma unroll
        for (int rr = 0; rr < 6; ++rr)
            C[rr] = *(const bf16x8*)(rowp + rr*8);   // 16B-aligned ds_read_b128
#pragma unroll
        for (int s = 0; s < 4; ++s) {
            acc[s] = __builtin_amdgcn_mfma_f32_32x32x16_bf16(cA0, C[s],   acc[s], 0, 0, 0);
            acc[s] = __builtin_amdgcn_mfma_f32_32x32x16_bf16(cA1, C[s+2], acc[s], 0, 0, 0);
        }
    }
}

__device__ __forceinline__ void compute_bases(unsigned base[4], int tid, int x0, int ytile) {
#pragma unroll
    for (int k = 0; k < 4; ++k) {
        int f = tid + 384*k;                    // float4 index [0,1536)
        int sl = f / 768;                       // x-slot (h) of this float4
        int g2 = f - sl*768;
        int fb = g2 / 24;                       // batch
        int r4 = (g2 - fb*24) * 4;              // offset in 96-float (y,c) run
        base[k] = ((unsigned)(fb*WDIM + x0 + 32*sl)*HDIM + (unsigned)ytile)*CDIM + r4;
    }
}

// Epilogue: 4 fully-unrolled LDS transpose rounds (static acc index), lgkm-only
// barriers; obA[4] must be pre-issued by the caller (hidden under main loop).
__device__ __forceinline__ void epilogue(const floatx16 acc[4], float* sOut,
                                         const unsigned base[4], fx4 obA[4],
                                         const float* __restrict__ obs,
                                         float* __restrict__ out,
                                         int tid, int n, int q, int c, int h,
                                         float& ls) {
    fx4 obB[4];
#pragma unroll
    for (int k = 0; k < 4; ++k)
        obB[k] = __builtin_nontemporal_load((const fx4*)&obs[base[k] + 8*HDIM*CDIM]);
#pragma unroll
    for (int t = 0; t < 4; ++t) {
        barrier_lgkm();    // all waves' prior LDS reads complete (LDS only)
#pragma unroll
        for (int rr = 0; rr < 16; ++rr) {
            int b = (rr & 3) + 8*(rr >> 2) + 4*q;   // D row = batch
            sOut[h*3072 + (b*32 + n)*3 + c] = acc[t][rr];  // bank 3n+c: conflict-free
        }
        barrier_lgkm();    // sOut writes visible (LDS only)
        fx4 cur[4];
#pragma unroll
        for (int k = 0; k < 4; ++k) { cur[k] = obA[k]; obA[k] = obB[k]; }
        if (t < 2) {       // depth-2 prefetch covers HBM/L3 latency
#pragma unroll
            for (int k = 0; k < 4; ++k)
                obB[k] = __builtin_nontemporal_load(
                    (const fx4*)&obs[base[k] + (unsigned)(t+2)*8*HDIM*CDIM]);
        }
#pragma unroll
        for (int k = 0; k < 4; ++k) {
            fx4 p = *(const fx4*)&sOut[4*(tid + 384*k)];
            __builtin_nontemporal_store(p, (fx4*)&out[base[k] + (unsigned)t*8*HDIM*CDIM]);
            fx4 d = cur[k] - p;
            ls += d[0]*d[0] + d[1]*d[1] + d[2]*d[2] + d[3]*d[3];
        }
    }
}

// Block = 384 threads = 6 waves; wave w -> (c = w>>1, h = w&1).
// Each block processes TWO y-tiles (z and z+8) in an intra-block pipeline:
// grid = 512 = exactly 2 blocks/CU -> SINGLE generation, all blocks resident.
__global__ __launch_bounds__(384, 3) void conv_mfma(
    const float* __restrict__ obs,    // [B,W,H,C]
    const float* __restrict__ img,    // [W,H,C]
    const __bf16* __restrict__ psfA,  // packed A-frags
    float* __restrict__ out)          // [B,W,H,C] pred, then loss scalar
{
    __shared__ __align__(16) unsigned char smem[LDS_BYTES];
    __bf16* sImgA = (__bf16*)smem;
    __bf16* sImgB = (__bf16*)(smem + SIMG_B_OFF);
    float*  sOutA = (float*)smem;
    float*  sOutB = (float*)(smem + SIMG_B_OFF);

    const int tid  = threadIdx.x;
    const int lane = tid & 63;
    const int w    = tid >> 6;      // wave 0..5
    const int c    = w >> 1;        // channel
    const int h    = w & 1;         // x-half
    const int n    = lane & 31;     // MFMA n (y within tile)
    const int q    = lane >> 5;     // k-half selector

    const int bx = blockIdx.x;      // [0,512)
    const int r8 = bx & 7;          // x mod-8 class
    const int g  = (bx >> 3) & 7;   // 64-wide x group
    const int z  = bx >> 6;         // [0,8)
    const int x0 = g*64 + r8;
    const int yt1 = z*32;           // tile 1 y-origin
    const int yt2 = (z + 8)*32;     // tile 2 y-origin

    const __bf16* pA = psfA + (size_t)c*(KPSF*2*64*8) + (size_t)lane*8;

    // ---- tile 1: stage -> main -> epilogue ----
    stage_tile(sImgA, img, tid, x0, yt1);
    __syncthreads();

    unsigned base1[4];
    compute_bases(base1, tid, x0, yt1);
    fx4 obA[4];
#pragma unroll
    for (int k = 0; k < 4; ++k)     // issue-early: arrives during main-1
        obA[k] = __builtin_nontemporal_load((const fx4*)&obs[base1[k]]);

    floatx16 acc1[4] = {};
    main_loop(acc1, pA, sImgA + c*TE + q*8 + h*32, n);

    float ls = 0.f;
    // epilogue-1 writes sOutA [0,24576) — entry barrier_lgkm orders vs main-1
    // reads of sImgA; its nt-stores drain under stage-2 + main-2.
    epilogue(acc1, sOutA, base1, obA, obs, out, tid, n, q, c, h, ls);

    // ---- tile 2: staged into disjoint LDS while epilogue-1 traffic drains ----
    stage_tile(sImgB, img, tid, x0, yt2);   // [24576,57840) disjoint from sOutA

    unsigned base2[4];
    compute_bases(base2, tid, x0, yt2);
#pragma unroll
    for (int k = 0; k < 4; ++k)     // issue-early: arrives during main-2
        obA[k] = __builtin_nontemporal_load((const fx4*)&obs[base2[k]]);

    barrier_lgkm();                 // sImgB writes visible to all waves

    floatx16 acc2[4] = {};
    main_loop(acc2, pA, sImgB + c*TE + q*8 + h*32, n);

    epilogue(acc2, sOutB, base2, obA, obs, out, tid, n, q, c, h, ls);

#pragma unroll
    for (int m = 32; m >= 1; m >>= 1) ls += __shfl_xor(ls, m, 64);
    if (lane == 0) atomicAdd(out + NPRED, ls * (1.0f/(float)NPRED));
}

extern "C" void kernel_launch(void* const* d_in, const int* in_sizes, int n_in,
                              void* d_out, int out_size, void* d_ws, size_t ws_size,
                              hipStream_t stream) {
    const float* obs = (const float*)d_in[0];   // observed_images [32,512,512,3]
    const float* img = (const float*)d_in[1];   // estimated_image [512,512,3]
    const float* psf = (const float*)d_in[2];   // psfs [32,32,32,1,3]
    float* out = (float*)d_out;                 // pred (25165824) + loss (1)
    __bf16* psfA = (__bf16*)d_ws;               // 196608 B packed psf frags

    pack_psf<<<192, 64, 0, stream>>>(psf, psfA, out + NPRED);
    conv_mfma<<<512, 384, 0, stream>>>(obs, img, psfA, out);
}

// Round 3
// 256.979 us; speedup vs baseline: 1.2268x; 1.2268x over previous
//
#include <hip/hip_runtime.h>
#include <hip/hip_bf16.h>

#define BATCH 32
#define WDIM 512
#define HDIM 512
#define CDIM 3
#define KPSF 32
#define NPRED (BATCH*WDIM*HDIM*CDIM)  // 25165824

#define TW 56        // tile width  (x): 4 outputs at stride 8 (span 25) + 31 taps
#define TH 63        // tile height (y): 32 + 31
#define TE (TW*TH)   // 3528 per channel
#define TALL (TW*TH*CDIM)  // 10584 dense elements

typedef __bf16 bf16x8 __attribute__((ext_vector_type(8)));
typedef float floatx16 __attribute__((ext_vector_type(16)));
typedef float fx4 __attribute__((ext_vector_type(4)));

// Workgroup barrier that does NOT drain vmcnt: only LDS ordering is required;
// global loads/stores stay in flight across it.
__device__ __forceinline__ void barrier_lgkm() {
    __asm__ volatile("s_waitcnt lgkmcnt(0)\n\ts_barrier" ::: "memory");
}

// Pack psf[b,i,j,0,c] (fp32) into MFMA A-fragment order (bf16):
// dst[((c*32 + j)*2 + h)*64 + lane][t] = psf[b=lane&31][i=16h+8*(lane>>5)+t][j][c]
__global__ __launch_bounds__(64) void pack_psf(const float* __restrict__ psf,
                                               __bf16* __restrict__ dst,
                                               float* __restrict__ loss) {
    if (blockIdx.x == 0 && threadIdx.x == 0) *loss = 0.f;
    int idx = blockIdx.x;              // [0,192) = ((c*32 + j)*2 + h)
    int h = idx & 1;
    int j = (idx >> 1) & 31;
    int c = idx >> 6;
    int lane = threadIdx.x;
    int b = lane & 31;
    int q = lane >> 5;
    bf16x8 v;
#pragma unroll
    for (int t = 0; t < 8; ++t) {
        int i = 16*h + 8*q + t;
        v[t] = (__bf16)psf[((size_t)(b*KPSF + i)*KPSF + j)*CDIM + c];
    }
    *(bf16x8*)(dst + (size_t)(idx*64 + lane)*8) = v;
}

// Block = 192 threads = 3 waves; wave = channel c. Each wave computes 4
// x-positions x0+8s (acc[4] = 64 ACC regs; ~148 total regs -> 3 waves/SIMD).
// 12 waves/CU = 4 resident blocks; 2048 small blocks overlap phases naturally.
__global__ __launch_bounds__(192, 3) void conv_mfma(
    const float* __restrict__ obs,    // [B,W,H,C]
    const float* __restrict__ img,    // [W,H,C]
    const __bf16* __restrict__ psfA,  // packed A-frags
    float* __restrict__ out)          // [B,W,H,C] pred, then loss scalar
{
    // sImg (main loop) and sOut (epilogue staging, 12 KB) share the same LDS.
    __shared__ __align__(16) unsigned char smem[CDIM*TE*2];  // 21168 B
    __bf16 (*sImg)[TE] = (__bf16 (*)[TE])smem;
    float* sOut = (float*)smem;

    const int tid  = threadIdx.x;
    const int lane = tid & 63;
    const int c    = tid >> 6;      // wave index = channel
    const int n    = lane & 31;     // MFMA n (y within tile)
    const int q    = lane >> 5;     // k-half selector

    const int bx = blockIdx.x;      // [0,2048)
    const int r8 = bx & 7;          // x mod-8 class
    const int g  = (bx >> 3) & 15;  // 32-wide x group
    const int yt = bx >> 7;         // y tile [0,16)
    const int x0 = g*32 + r8;       // wave's x's = x0 + 8s, s=0..3
    const int ytile = yt*32;

    // ---- stage transposed image tile ----
    const bool interior = (x0 >= 15) && (x0 <= WDIM - 41) &&
                          (ytile >= 15) && (ytile <= HDIM - 48);
    if (interior) {
        // float4 path: per x-row, the 189-float column run starts at a uniform
        // misalignment p2; load alignment-shifted float4 slots, scatter to LDS.
        const int col0 = (ytile - 15)*3;           // >= 0
        const int p2 = col0 & 3;
        const float* gb = img + (size_t)(x0 - 15)*(HDIM*CDIM) + (col0 - p2);
#pragma unroll 2
        for (int f = tid; f < 56*48; f += 192) {
            int r = f / 48;                        // x-row 0..55
            int v = f - r*48;                      // float4 slot 0..47
            fx4 val = *(const fx4*)(gb + (size_t)r*(HDIM*CDIM) + 4*v);
            int d = 4*v - p2;                      // col offset of val[0]
#pragma unroll
            for (int u = 0; u < 4; ++u) {
                int dd = d + u;
                if (dd >= 0 && dd < 189) {
                    int yl = (dd*171) >> 9;        // dd/3 for dd<511
                    int cc = dd - 3*yl;
                    sImg[cc][yl*TW + r] = (__bf16)val[u];
                }
            }
        }
    } else {
#pragma unroll 4
        for (int e = tid; e < TALL; e += 192) {
            int xl = e / (TH*CDIM);
            int rr = e - xl*(TH*CDIM);
            int yl = rr / 3;
            int cc = rr - yl*3;
            int xg = x0 + xl - 15;
            int yg = ytile + yl - 15;
            float v = 0.f;
            if ((unsigned)xg < WDIM && (unsigned)yg < HDIM)
                v = img[((size_t)xg*HDIM + yg)*CDIM + cc];
            sImg[cc][yl*TW + xl] = (__bf16)v;
        }
    }
    __syncthreads();

    // ---- issue-early obs loads for epilogue round 0 (hidden under main) ----
    unsigned base[4];
#pragma unroll
    for (int k = 0; k < 4; ++k) {
        int f = tid + 192*k;                    // float4 index [0,768)
        int fb = f / 24;                        // batch
        int r4 = (f - fb*24) * 4;               // offset in 96-float (y,c) run
        base[k] = ((unsigned)(fb*WDIM + x0)*HDIM + (unsigned)ytile)*CDIM + r4;
    }
    fx4 obA[4];
#pragma unroll
    for (int k = 0; k < 4; ++k)
        obA[k] = __builtin_nontemporal_load((const fx4*)&obs[base[k]]);

    // ---- main loop: LDS reads + MFMA, A(j+1) prefetched from L2 ----
    floatx16 acc[4] = {};
    const __bf16* pA = psfA + (size_t)c*(KPSF*2*64*8) + (size_t)lane*8;
    const __bf16* sI = (const __bf16*)&sImg[c][q*8];

    bf16x8 A0 = *(const bf16x8*)(pA);
    bf16x8 A1 = *(const bf16x8*)(pA + 512);
#pragma unroll 2
    for (int j = 0; j < 32; ++j) {
        bf16x8 cA0 = A0, cA1 = A1;
        if (j < 31) {
            A0 = *(const bf16x8*)(pA + (size_t)(j+1)*1024);
            A1 = *(const bf16x8*)(pA + (size_t)(j+1)*1024 + 512);
        }
        const __bf16* rowp = sI + (n + j)*TW;
        bf16x8 C[6];
#pragma unroll
        for (int rr = 0; rr < 6; ++rr)
            C[rr] = *(const bf16x8*)(rowp + rr*8);   // 16B-aligned ds_read_b128
#pragma unroll
        for (int s = 0; s < 4; ++s) {
            acc[s] = __builtin_amdgcn_mfma_f32_32x32x16_bf16(cA0, C[s],   acc[s], 0, 0, 0);
            acc[s] = __builtin_amdgcn_mfma_f32_32x32x16_bf16(cA1, C[s+2], acc[s], 0, 0, 0);
        }
    }

    // ---- epilogue: 4 fully-unrolled LDS transpose rounds (static acc index),
    // lgkm-only barriers; round t handles output x = x0 + 8t.
    float ls = 0.f;
    fx4 obB[4];
#pragma unroll
    for (int k = 0; k < 4; ++k)
        obB[k] = __builtin_nontemporal_load((const fx4*)&obs[base[k] + 8*HDIM*CDIM]);

#pragma unroll
    for (int t = 0; t < 4; ++t) {
        barrier_lgkm();    // all waves' prior LDS reads complete (LDS only)
#pragma unroll
        for (int rr = 0; rr < 16; ++rr) {
            int b = (rr & 3) + 8*(rr >> 2) + 4*q;   // D row = batch
            sOut[(b*32 + n)*3 + c] = acc[t][rr];    // bank 3n+c: conflict-free
        }
        barrier_lgkm();    // sOut writes visible (LDS only)
        fx4 cur[4];
#pragma unroll
        for (int k = 0; k < 4; ++k) { cur[k] = obA[k]; obA[k] = obB[k]; }
        if (t < 2) {       // depth-2 prefetch covers HBM/L3 latency
#pragma unroll
            for (int k = 0; k < 4; ++k)
                obB[k] = __builtin_nontemporal_load(
                    (const fx4*)&obs[base[k] + (unsigned)(t+2)*8*HDIM*CDIM]);
        }
#pragma unroll
        for (int k = 0; k < 4; ++k) {
            fx4 p = *(const fx4*)&sOut[4*(tid + 192*k)];
            __builtin_nontemporal_store(p, (fx4*)&out[base[k] + (unsigned)t*8*HDIM*CDIM]);
            fx4 d = cur[k] - p;
            ls += d[0]*d[0] + d[1]*d[1] + d[2]*d[2] + d[3]*d[3];
        }
    }

#pragma unroll
    for (int m = 32; m >= 1; m >>= 1) ls += __shfl_xor(ls, m, 64);
    if (lane == 0) atomicAdd(out + NPRED, ls * (1.0f/(float)NPRED));
}

extern "C" void kernel_launch(void* const* d_in, const int* in_sizes, int n_in,
                              void* d_out, int out_size, void* d_ws, size_t ws_size,
                              hipStream_t stream) {
    const float* obs = (const float*)d_in[0];   // observed_images [32,512,512,3]
    const float* img = (const float*)d_in[1];   // estimated_image [512,512,3]
    const float* psf = (const float*)d_in[2];   // psfs [32,32,32,1,3]
    float* out = (float*)d_out;                 // pred (25165824) + loss (1)
    __bf16* psfA = (__bf16*)d_ws;               // 196608 B packed psf frags

    pack_psf<<<192, 64, 0, stream>>>(psf, psfA, out + NPRED);
    conv_mfma<<<2048, 192, 0, stream>>>(obs, img, psfA, out);
}